// Round 6
// baseline (263.011 us; speedup 1.0000x reference)
//
#include <hip/hip_runtime.h>
#include <math.h>

#define DIMC 96
#define DIN  192
#define NST  16
#define RNK  6
#define KD   4
#define HH   64
#define WWD  64
#define LL   4096
#define BB   2
#define NC   128   // number of chunks
#define CH   32    // chunk length (NC*CH == LL)
#define CPK  48    // record floats: B(16) | C(16) | dts(6) | pad(10)

__device__ __forceinline__ int pos_of(int k, int l) {
    int t = ((l & 63) << 6) | (l >> 6);       // 64x64 transpose
    switch (k) {
        case 0: return l;
        case 1: return t;
        case 2: return LL - 1 - l;
        default: return ((((LL-1-l) & 63) << 6) | ((LL-1-l) >> 6));
    }
}

__device__ __forceinline__ float silu_f(float v) {
    return v / (1.f + __expf(-v));
}

// ---------------- K1: |x-y|, LN(96), in_proj (direct Win reads) ----------------
// Side-task prologue: builds wT3 (for K3) and WoutT (for K7).
__global__ __launch_bounds__(1024) void k1_ln_inproj(
    const float* __restrict__ x, const float* __restrict__ y,
    const float* __restrict__ lnw, const float* __restrict__ lnb,
    const float* __restrict__ Win, const float* __restrict__ Wout,
    const float* __restrict__ xpw,
    float* __restrict__ diff, float* __restrict__ xm, float* __restrict__ zbuf,
    float* __restrict__ wT3, float* __restrict__ WoutT)
{
    __shared__ float hT[96*65];
    __shared__ float ps1[16*64], ps2[16*64];
    __shared__ float mus[64], rss[64];
    int t = threadIdx.x;
    int ptile = blockIdx.x >> 1, cgrp = blockIdx.x & 1;
    int p0 = ptile*64;

    // ---- side-task: weight prep for later kernels ----
    {
        int gid = blockIdx.x*1024 + t;
        if (gid < KD*192*CPK) {                       // wT3[k][j][c']
            int kk = gid / (192*CPK); int rem = gid - kk*192*CPK;
            int j = rem / CPK, c = rem - j*CPK;
            float v = 0.f;
            if (c < 16)       v = xpw[((size_t)kk*(RNK+2*NST) + RNK + c)*DIN + j];
            else if (c < 32)  v = xpw[((size_t)kk*(RNK+2*NST) + RNK + NST + (c-16))*DIN + j];
            else if (c < 38)  v = xpw[((size_t)kk*(RNK+2*NST) + (c-32))*DIN + j];
            wT3[gid] = v;
        } else if (gid < KD*192*CPK + 192*96) {       // WoutT[j][o]
            int i = gid - KD*192*CPK;
            int j = i / 96, o = i - j*96;
            WoutT[i] = Wout[o*192 + j];
        }
    }

    // ---- stage |x-y| with float4 loads (1536 quads = 64 pos x 24 quads) ----
    #pragma unroll
    for (int s = 0; s < 2; s++) {
        int i4 = t + 1024*s;
        if (i4 < 1536) {
            float4 xv = *(const float4*)&x[(size_t)p0*96 + i4*4];
            float4 yv = *(const float4*)&y[(size_t)p0*96 + i4*4];
            float4 v = make_float4(fabsf(xv.x - yv.x), fabsf(xv.y - yv.y),
                                   fabsf(xv.z - yv.z), fabsf(xv.w - yv.w));
            if (cgrp == 0) *(float4*)&diff[(size_t)p0*96 + i4*4] = v;
            int pos = i4 / 24, q = i4 - pos*24;
            int ch = q << 2;
            hT[(ch+0)*65 + pos] = v.x;
            hT[(ch+1)*65 + pos] = v.y;
            hT[(ch+2)*65 + pos] = v.z;
            hT[(ch+3)*65 + pos] = v.w;
        }
    }
    __syncthreads();
    {
        int pos = t & 63, part = t >> 6;
        float s1 = 0.f, s2 = 0.f;
        #pragma unroll
        for (int m = 0; m < 6; m++) {
            float v = hT[(part*6 + m)*65 + pos];
            s1 += v; s2 += v*v;
        }
        ps1[part*64 + pos] = s1; ps2[part*64 + pos] = s2;
    }
    __syncthreads();
    if (t < 64) {
        float S1 = 0.f, S2 = 0.f;
        #pragma unroll
        for (int i = 0; i < 16; i++) { S1 += ps1[i*64 + t]; S2 += ps2[i*64 + t]; }
        float mu = S1 * (1.f/96.f);
        float var = S2 * (1.f/96.f) - mu*mu;
        mus[t] = mu; rss[t] = rsqrtf(var + 1e-5f);
    }
    __syncthreads();
    #pragma unroll
    for (int s = 0; s < 6; s++) {
        int i = t + 1024*s;
        int pos = i / 96, ch = i - pos*96;
        hT[ch*65 + pos] = (hT[ch*65 + pos] - mus[pos]) * rss[pos] * lnw[ch] + lnb[ch];
    }
    __syncthreads();

    int w = __builtin_amdgcn_readfirstlane(t >> 6);
    int lane = t & 63;
    int c0 = cgrp*192 + w*12;
    const float* wrows = Win + (size_t)c0*96;   // 12 rows, stride 96, wave-uniform
    float acc[12];
    #pragma unroll
    for (int cc = 0; cc < 12; cc++) acc[cc] = 0.f;
    #pragma unroll 2
    for (int j = 0; j < 96; j++) {
        float u = hT[j*65 + lane];
        #pragma unroll
        for (int cc = 0; cc < 12; cc++) acc[cc] += u * wrows[cc*96 + j];
    }
    size_t p = (size_t)(p0 + lane);
    float* dst = (c0 < 192) ? (xm + p*192 + c0) : (zbuf + p*192 + (c0 - 192));
    #pragma unroll
    for (int q = 0; q < 3; q++)
        *(float4*)&dst[4*q] = make_float4(acc[4*q], acc[4*q+1], acc[4*q+2], acc[4*q+3]);
}

// ---------------- K2: depthwise 3x3 conv + bias + SiLU ----------------
__global__ __launch_bounds__(192) void k2_conv(
    const float* __restrict__ xm, const float* __restrict__ cw,
    const float* __restrict__ cb, float* __restrict__ xconv)
{
    int p = blockIdx.x;
    int d = threadIdx.x;
    int b = p >> 12;
    int l = p & (LL - 1);
    int hh = l >> 6, ww = l & 63;
    float acc = cb[d];
    const float* wd = cw + d*9;
    #pragma unroll
    for (int di = -1; di <= 1; di++) {
        int h2 = hh + di;
        if ((unsigned)h2 < HH) {
            #pragma unroll
            for (int dj = -1; dj <= 1; dj++) {
                int w2 = ww + dj;
                if ((unsigned)w2 < WWD)
                    acc += wd[(di+1)*3 + (dj+1)] * xm[((size_t)b*LL + h2*WWD + w2)*DIN + d];
            }
        }
    }
    xconv[(size_t)p*DIN + d] = silu_f(acc);
}

// ---------------- K3: 4-direction x_proj, float4 stage + swizzled b128 LDS ----------------
__global__ __launch_bounds__(512) void k3_xproj(
    const float* __restrict__ xconv, const float* __restrict__ wT3,
    float* __restrict__ XDK)
{
    __shared__ float uT[64*192];   // [pos][ch], float4-quad XOR swizzle
    int t = threadIdx.x;
    int ptile = blockIdx.x >> 1, wgrp = blockIdx.x & 1;
    int p0 = ptile*64;

    #pragma unroll
    for (int s = 0; s < 6; s++) {
        int i4 = t + 512*s;                // 3072 quads = 64 pos x 48 quads
        int pos = i4 / 48, q = i4 - pos*48;
        float4 v = *(const float4*)&xconv[(size_t)(p0 + pos)*192 + (q << 2)];
        *(float4*)&uT[pos*192 + ((q ^ (pos & 7)) << 2)] = v;
    }
    __syncthreads();

    int w = __builtin_amdgcn_readfirstlane(t >> 6);   // 0..7
    int slot = wgrp*8 + w;                             // 0..15
    int k = slot >> 2, cq = slot & 3;
    int lane = t & 63;
    int c0 = cq*12;
    const float* wp = wT3 + (size_t)k*192*CPK + c0;
    const float* urow = uT + lane*192;
    int sw = lane & 7;
    float acc[12];
    #pragma unroll
    for (int cc = 0; cc < 12; cc++) acc[cc] = 0.f;
    #pragma unroll 4
    for (int j4 = 0; j4 < 48; j4++) {
        float4 u4 = *(const float4*)&urow[((j4 ^ sw) << 2)];   // channels 4*j4..4*j4+3
        const float* wrow = wp + (j4*4)*CPK;
        #pragma unroll
        for (int cc = 0; cc < 12; cc++) acc[cc] += u4.x * wrow[cc];
        #pragma unroll
        for (int cc = 0; cc < 12; cc++) acc[cc] += u4.y * wrow[CPK + cc];
        #pragma unroll
        for (int cc = 0; cc < 12; cc++) acc[cc] += u4.z * wrow[2*CPK + cc];
        #pragma unroll
        for (int cc = 0; cc < 12; cc++) acc[cc] += u4.w * wrow[3*CPK + cc];
    }
    int p = p0 + lane;
    int b = p >> 12;
    int s = p & (LL - 1);
    int ts = ((s & 63) << 6) | (s >> 6);
    int l;
    switch (k) {
        case 0: l = s; break;
        case 1: l = ts; break;
        case 2: l = LL - 1 - s; break;
        default: l = LL - 1 - ts; break;
    }
    float* dst = XDK + ((size_t)(b*KD + k)*LL + l)*CPK + c0;
    #pragma unroll
    for (int q = 0; q < 3; q++)
        *(float4*)&dst[4*q] = make_float4(acc[4*q], acc[4*q+1], acc[4*q+2], acc[4*q+3]);
}

// ---------------- K4: scan pass A — h over chunk + S = sum(delta) ----------------
__global__ __launch_bounds__(192) void k4_scanA(
    const float* __restrict__ xconv, const float* __restrict__ XDK,
    const float* __restrict__ dtw, const float* __restrict__ dtb,
    const float* __restrict__ A_log,
    float* __restrict__ Sarr, float* __restrict__ Q)
{
    int blk = blockIdx.x;              // bk*NC + c
    int c  = blk & (NC - 1);
    int bk = blk >> 7;
    int k  = bk & 3;
    int b  = bk >> 2;
    int d  = threadIdx.x;
    float dw[RNK];
    #pragma unroll
    for (int r = 0; r < RNK; r++) dw[r] = dtw[((size_t)k*DIN + d)*RNK + r];
    float bias = dtb[k*DIN + d];
    float A[NST];
    #pragma unroll
    for (int n = 0; n < NST; n++) A[n] = -__expf(A_log[((size_t)k*DIN + d)*NST + n]);
    bool fastA = true;
    #pragma unroll
    for (int n = 1; n < NST; n++)
        fastA = fastA && (fabsf(A[n] - (float)(n+1)*A[0]) <= 1e-4f*(float)(n+1));

    float h[NST];
    #pragma unroll
    for (int n = 0; n < NST; n++) h[n] = 0.f;
    float S = 0.f;

    size_t rb = ((size_t)bk*LL + c*CH)*CPK;
    if (fastA) {
        #pragma unroll 2
        for (int step = 0; step < CH; step++) {
            const float* rec = XDK + rb + step*CPK;
            float dl = bias;
            #pragma unroll
            for (int r = 0; r < RNK; r++) dl += rec[32 + r] * dw[r];
            dl = (dl > 20.f) ? dl : __logf(1.f + __expf(dl));
            int l = c*CH + step;
            float uu = xconv[((size_t)b*LL + pos_of(k, l))*DIN + d];
            float du = dl * uu;
            S += dl;
            float e1 = __expf(dl * A[0]);
            float e2 = e1*e1, e4 = e2*e2;
            float p0 = e1, p1 = e2, p2 = e2*e1, p3 = e4;
            #pragma unroll
            for (int g = 0; g < 4; g++) {
                h[4*g+0] = p0*h[4*g+0] + du*rec[4*g+0];
                h[4*g+1] = p1*h[4*g+1] + du*rec[4*g+1];
                h[4*g+2] = p2*h[4*g+2] + du*rec[4*g+2];
                h[4*g+3] = p3*h[4*g+3] + du*rec[4*g+3];
                if (g < 3) { p0 *= e4; p1 *= e4; p2 *= e4; p3 *= e4; }
            }
        }
    } else {
        #pragma unroll 2
        for (int step = 0; step < CH; step++) {
            const float* rec = XDK + rb + step*CPK;
            float dl = bias;
            #pragma unroll
            for (int r = 0; r < RNK; r++) dl += rec[32 + r] * dw[r];
            dl = (dl > 20.f) ? dl : __logf(1.f + __expf(dl));
            int l = c*CH + step;
            float uu = xconv[((size_t)b*LL + pos_of(k, l))*DIN + d];
            float du = dl * uu;
            S += dl;
            #pragma unroll
            for (int n = 0; n < NST; n++) {
                float a = __expf(dl * A[n]);
                h[n] = a*h[n] + du*rec[n];
            }
        }
    }
    Sarr[(size_t)blk*DIN + d] = S;
    size_t qb = (size_t)blk*NST*DIN + d;
    #pragma unroll
    for (int n = 0; n < NST; n++) Q[qb + n*DIN] = h[n];
}

// ---------------- K5: compose chunk transfers; Q becomes per-chunk init state ----------------
__global__ __launch_bounds__(256) void k5_scanB(
    const float* __restrict__ A_log, const float* __restrict__ Sarr,
    float* __restrict__ Q)
{
    int idx = blockIdx.x*256 + threadIdx.x;
    if (idx >= BB*KD*NST*DIN) return;
    int d = idx % DIN;
    int rest = idx / DIN;
    int n = rest % NST; rest /= NST;
    int k = rest & 3;
    int b = rest >> 2;
    int bk = b*KD + k;
    float A = -__expf(A_log[((size_t)k*DIN + d)*NST + n]);
    size_t qstride = (size_t)NST*DIN;
    size_t qbase = (size_t)bk*NC*qstride + n*DIN + d;
    size_t sbase = (size_t)bk*NC*DIN + d;
    float h = 0.f;
    #pragma unroll 4
    for (int c = 0; c < NC; c++) {
        float s = Sarr[sbase + c*DIN];
        float q = Q[qbase + c*qstride];
        Q[qbase + c*qstride] = h;
        h = __expf(A*s)*h + q;
    }
}

// ---------------- K6: scan pass C — replay, emit y at SPATIAL position ----------------
__global__ __launch_bounds__(192) void k6_scanC(
    const float* __restrict__ xconv, const float* __restrict__ XDK,
    const float* __restrict__ dtw, const float* __restrict__ dtb,
    const float* __restrict__ A_log, const float* __restrict__ Ds,
    const float* __restrict__ Q, float* __restrict__ outy)
{
    int blk = blockIdx.x;
    int c  = blk & (NC - 1);
    int bk = blk >> 7;
    int k  = bk & 3;
    int b  = bk >> 2;
    int d  = threadIdx.x;
    float dw[RNK];
    #pragma unroll
    for (int r = 0; r < RNK; r++) dw[r] = dtw[((size_t)k*DIN + d)*RNK + r];
    float bias = dtb[k*DIN + d];
    float A[NST];
    #pragma unroll
    for (int n = 0; n < NST; n++) A[n] = -__expf(A_log[((size_t)k*DIN + d)*NST + n]);
    bool fastA = true;
    #pragma unroll
    for (int n = 1; n < NST; n++)
        fastA = fastA && (fabsf(A[n] - (float)(n+1)*A[0]) <= 1e-4f*(float)(n+1));
    float h[NST];
    size_t qb = (size_t)blk*NST*DIN + d;
    #pragma unroll
    for (int n = 0; n < NST; n++) h[n] = Q[qb + n*DIN];
    float Dv = Ds[k*DIN + d];

    size_t rb = ((size_t)bk*LL + c*CH)*CPK;
    if (fastA) {
        #pragma unroll 2
        for (int step = 0; step < CH; step++) {
            const float* rec = XDK + rb + step*CPK;
            float dl = bias;
            #pragma unroll
            for (int r = 0; r < RNK; r++) dl += rec[32 + r] * dw[r];
            dl = (dl > 20.f) ? dl : __logf(1.f + __expf(dl));
            int l = c*CH + step;
            int sp = pos_of(k, l);
            float uu = xconv[((size_t)b*LL + sp)*DIN + d];
            float du = dl * uu;
            float e1 = __expf(dl * A[0]);
            float e2 = e1*e1, e4 = e2*e2;
            float p0 = e1, p1 = e2, p2 = e2*e1, p3 = e4;
            float yv = 0.f;
            #pragma unroll
            for (int g = 0; g < 4; g++) {
                h[4*g+0] = p0*h[4*g+0] + du*rec[4*g+0];
                h[4*g+1] = p1*h[4*g+1] + du*rec[4*g+1];
                h[4*g+2] = p2*h[4*g+2] + du*rec[4*g+2];
                h[4*g+3] = p3*h[4*g+3] + du*rec[4*g+3];
                yv += h[4*g+0]*rec[16+4*g+0] + h[4*g+1]*rec[16+4*g+1]
                    + h[4*g+2]*rec[16+4*g+2] + h[4*g+3]*rec[16+4*g+3];
                if (g < 3) { p0 *= e4; p1 *= e4; p2 *= e4; p3 *= e4; }
            }
            outy[((size_t)bk*LL + sp)*DIN + d] = yv + Dv*uu;
        }
    } else {
        #pragma unroll 2
        for (int step = 0; step < CH; step++) {
            const float* rec = XDK + rb + step*CPK;
            float dl = bias;
            #pragma unroll
            for (int r = 0; r < RNK; r++) dl += rec[32 + r] * dw[r];
            dl = (dl > 20.f) ? dl : __logf(1.f + __expf(dl));
            int l = c*CH + step;
            int sp = pos_of(k, l);
            float uu = xconv[((size_t)b*LL + sp)*DIN + d];
            float du = dl * uu;
            float yv = 0.f;
            #pragma unroll
            for (int n = 0; n < NST; n++) {
                float a = __expf(dl * A[n]);
                h[n] = a*h[n] + du*rec[n];
                yv += h[n] * rec[16 + n];
            }
            outy[((size_t)bk*LL + sp)*DIN + d] = yv + Dv*uu;
        }
    }
}

// ---------------- K7: combine, LN(192), gate, out_proj, residual ----------------
// float4 stage (outy x4 summed), quad-XOR-swizzled [pos][ch] LDS, b128 reads.
__global__ __launch_bounds__(512) void k7_out(
    const float* __restrict__ outy, const float* __restrict__ zbuf,
    const float* __restrict__ diff, const float* __restrict__ onw,
    const float* __restrict__ onb, const float* __restrict__ WoutT,
    float* __restrict__ out)
{
    __shared__ float uT[64*192];   // [pos][ch], float4-quad XOR swizzle
    __shared__ float ps1[8*64], ps2[8*64];
    __shared__ float mus[64], rss[64];
    int t = threadIdx.x;
    int ptile = blockIdx.x >> 1, chalf = blockIdx.x & 1;
    int p0 = ptile*64;
    int b = p0 >> 12;
    int l0 = p0 & (LL - 1);
    const size_t seg4 = (size_t)LL*DIN/4;
    const float4* o0 = (const float4*)(outy + ((size_t)(b*KD)*LL + l0)*DIN);

    #pragma unroll
    for (int s = 0; s < 6; s++) {
        int i4 = t + 512*s;                // 3072 quads = 64 pos x 48 quads
        float4 a = o0[i4];
        float4 bq = o0[i4 + seg4];
        float4 cq = o0[i4 + 2*seg4];
        float4 dq = o0[i4 + 3*seg4];
        float4 v = make_float4(a.x+bq.x+cq.x+dq.x, a.y+bq.y+cq.y+dq.y,
                               a.z+bq.z+cq.z+dq.z, a.w+bq.w+cq.w+dq.w);
        int pos = i4 / 48, q = i4 - pos*48;
        *(float4*)&uT[pos*192 + ((q ^ (pos & 7)) << 2)] = v;
    }
    __syncthreads();
    {
        int pos = t & 63, part = t >> 6;   // 8 parts x 6 quads = 48 quads
        float s1 = 0.f, s2 = 0.f;
        #pragma unroll
        for (int m = 0; m < 6; m++) {
            int q = part*6 + m;
            float4 v = *(const float4*)&uT[pos*192 + ((q ^ (pos & 7)) << 2)];
            s1 += v.x + v.y + v.z + v.w;
            s2 += v.x*v.x + v.y*v.y + v.z*v.z + v.w*v.w;
        }
        ps1[part*64 + pos] = s1; ps2[part*64 + pos] = s2;
    }
    __syncthreads();
    if (t < 64) {
        float S1 = 0.f, S2 = 0.f;
        #pragma unroll
        for (int i = 0; i < 8; i++) { S1 += ps1[i*64 + t]; S2 += ps2[i*64 + t]; }
        float mu = S1 * (1.f/192.f);
        float var = S2 * (1.f/192.f) - mu*mu;
        mus[t] = mu; rss[t] = rsqrtf(var + 1e-5f);
    }
    __syncthreads();
    {
        const float4* zb = (const float4*)(zbuf + (size_t)p0*DIN);
        #pragma unroll
        for (int s = 0; s < 6; s++) {
            int i4 = t + 512*s;
            int pos = i4 / 48, q = i4 - pos*48;
            int ch = q << 2;
            float* slot = &uT[pos*192 + ((q ^ (pos & 7)) << 2)];
            float4 v = *(float4*)slot;
            float4 z = zb[i4];
            float4 wv = *(const float4*)&onw[ch];
            float4 bv = *(const float4*)&onb[ch];
            float mu = mus[pos], rs = rss[pos];
            v.x = ((v.x - mu)*rs*wv.x + bv.x) * silu_f(z.x);
            v.y = ((v.y - mu)*rs*wv.y + bv.y) * silu_f(z.y);
            v.z = ((v.z - mu)*rs*wv.z + bv.z) * silu_f(z.z);
            v.w = ((v.w - mu)*rs*wv.w + bv.w) * silu_f(z.w);
            *(float4*)slot = v;
        }
    }
    __syncthreads();

    int w = __builtin_amdgcn_readfirstlane(t >> 6);   // 0..7
    int lane = t & 63;
    int c0 = chalf*48 + w*6;                          // 8 waves x 6 output cols
    const float* wp = WoutT + c0;
    const float* urow = uT + lane*192;
    int sw = lane & 7;
    float acc[6];
    #pragma unroll
    for (int cc = 0; cc < 6; cc++) acc[cc] = 0.f;
    #pragma unroll 4
    for (int jq = 0; jq < 48; jq++) {
        float4 u4 = *(const float4*)&urow[((jq ^ sw) << 2)];   // channels 4*jq..4*jq+3
        const float* wr = wp + (jq*4)*96;
        #pragma unroll
        for (int cc = 0; cc < 6; cc++) acc[cc] += u4.x * wr[cc];
        #pragma unroll
        for (int cc = 0; cc < 6; cc++) acc[cc] += u4.y * wr[96 + cc];
        #pragma unroll
        for (int cc = 0; cc < 6; cc++) acc[cc] += u4.z * wr[192 + cc];
        #pragma unroll
        for (int cc = 0; cc < 6; cc++) acc[cc] += u4.w * wr[288 + cc];
    }
    size_t p = (size_t)(p0 + lane);
    #pragma unroll
    for (int q = 0; q < 3; q++) {
        float2 dv = *(const float2*)&diff[p*96 + c0 + 2*q];
        *(float2*)&out[p*96 + c0 + 2*q] =
            make_float2(acc[2*q] + dv.x, acc[2*q+1] + dv.y);
    }
}

extern "C" void kernel_launch(void* const* d_in, const int* in_sizes, int n_in,
                              void* d_out, int out_size, void* d_ws, size_t ws_size,
                              hipStream_t stream)
{
    const float* x       = (const float*)d_in[0];
    const float* y       = (const float*)d_in[1];
    const float* ln_w    = (const float*)d_in[2];
    const float* ln_b    = (const float*)d_in[3];
    const float* in_proj = (const float*)d_in[4];
    const float* conv_w  = (const float*)d_in[5];
    const float* conv_b  = (const float*)d_in[6];
    const float* x_proj  = (const float*)d_in[7];
    const float* dt_w    = (const float*)d_in[8];
    const float* dt_b    = (const float*)d_in[9];
    const float* A_log   = (const float*)d_in[10];
    const float* Ds      = (const float*)d_in[11];
    const float* onw     = (const float*)d_in[12];
    const float* onb     = (const float*)d_in[13];
    const float* out_w   = (const float*)d_in[14];
    float* out = (float*)d_out;

    float* ws    = (float*)d_ws;
    float* diff  = ws;                       // 786432
    float* zbuf  = diff  + 786432;           // 1572864
    float* xm    = zbuf  + 1572864;          // 1572864
    float* xconv = xm    + 1572864;          // 1572864
    float* XDK   = xconv + 1572864;          // 1572864
    float* outy  = XDK   + 1572864;          // 6291456
    float* Qbuf  = outy  + 6291456;          // 3145728 (1024 blk x 16 x 192)
    float* Sarr  = Qbuf  + 6291456;          // 196608
    float* WoutT = Sarr  + 393216;           // 18432
    float* wT3   = WoutT + 18432;            // 36864

    const int BL = BB * LL;                  // 8192

    hipLaunchKernelGGL(k1_ln_inproj, dim3(BL/64*2), dim3(1024), 0, stream,
                       x, y, ln_w, ln_b, in_proj, out_w, x_proj,
                       diff, xm, zbuf, wT3, WoutT);
    hipLaunchKernelGGL(k2_conv, dim3(BL), dim3(DIN), 0, stream,
                       xm, conv_w, conv_b, xconv);
    hipLaunchKernelGGL(k3_xproj, dim3(BL/64*2), dim3(512), 0, stream,
                       xconv, wT3, XDK);
    hipLaunchKernelGGL(k4_scanA, dim3(BB*KD*NC), dim3(DIN), 0, stream,
                       xconv, XDK, dt_w, dt_b, A_log, Sarr, Qbuf);
    hipLaunchKernelGGL(k5_scanB, dim3((BB*KD*NST*DIN + 255)/256), dim3(256), 0, stream,
                       A_log, Sarr, Qbuf);
    hipLaunchKernelGGL(k6_scanC, dim3(BB*KD*NC), dim3(DIN), 0, stream,
                       xconv, XDK, dt_w, dt_b, A_log, Ds, Qbuf, outy);
    hipLaunchKernelGGL(k7_out, dim3(BL/64*2), dim3(512), 0, stream,
                       outy, zbuf, diff, onw, onb, WoutT, out);
}

// Round 7
// 245.645 us; speedup vs baseline: 1.0707x; 1.0707x over previous
//
#include <hip/hip_runtime.h>
#include <math.h>

#define DIMC 96
#define DIN  192
#define NST  16
#define RNK  6
#define KD   4
#define HH   64
#define WWD  64
#define LL   4096
#define BB   2
#define NC   128   // number of chunks
#define CH   32    // chunk length (NC*CH == LL)
#define CPK  48    // record floats: B(16) | C(16) | dts(6) | pad(10)
#define SCANB_BLKS 96   // blocks doing the chunk-compose work in k5
#define ZERO_BLKS  384  // blocks zeroing outc in k5

__device__ __forceinline__ int pos_of(int k, int l) {
    int t = ((l & 63) << 6) | (l >> 6);       // 64x64 transpose
    switch (k) {
        case 0: return l;
        case 1: return t;
        case 2: return LL - 1 - l;
        default: return ((((LL-1-l) & 63) << 6) | ((LL-1-l) >> 6));
    }
}

__device__ __forceinline__ float silu_f(float v) {
    return v / (1.f + __expf(-v));
}

// ---------------- K1: |x-y|, LN(96), in_proj (direct Win reads) ----------------
// Side-task prologue: builds wT3 (for K3) and WoutT (for K7).
__global__ __launch_bounds__(1024) void k1_ln_inproj(
    const float* __restrict__ x, const float* __restrict__ y,
    const float* __restrict__ lnw, const float* __restrict__ lnb,
    const float* __restrict__ Win, const float* __restrict__ Wout,
    const float* __restrict__ xpw,
    float* __restrict__ diff, float* __restrict__ xm, float* __restrict__ zbuf,
    float* __restrict__ wT3, float* __restrict__ WoutT)
{
    __shared__ float hT[96*65];
    __shared__ float ps1[16*64], ps2[16*64];
    __shared__ float mus[64], rss[64];
    int t = threadIdx.x;
    int ptile = blockIdx.x >> 1, cgrp = blockIdx.x & 1;
    int p0 = ptile*64;

    // ---- side-task: weight prep for later kernels ----
    {
        int gid = blockIdx.x*1024 + t;
        if (gid < KD*192*CPK) {                       // wT3[k][j][c']
            int kk = gid / (192*CPK); int rem = gid - kk*192*CPK;
            int j = rem / CPK, c = rem - j*CPK;
            float v = 0.f;
            if (c < 16)       v = xpw[((size_t)kk*(RNK+2*NST) + RNK + c)*DIN + j];
            else if (c < 32)  v = xpw[((size_t)kk*(RNK+2*NST) + RNK + NST + (c-16))*DIN + j];
            else if (c < 38)  v = xpw[((size_t)kk*(RNK+2*NST) + (c-32))*DIN + j];
            wT3[gid] = v;
        } else if (gid < KD*192*CPK + 192*96) {       // WoutT[j][o]
            int i = gid - KD*192*CPK;
            int j = i / 96, o = i - j*96;
            WoutT[i] = Wout[o*192 + j];
        }
    }

    #pragma unroll
    for (int s = 0; s < 6; s++) {
        int i = t + 1024*s;
        float v = fabsf(x[(size_t)p0*96 + i] - y[(size_t)p0*96 + i]);
        if (cgrp == 0) diff[(size_t)p0*96 + i] = v;
        int pos = i / 96, ch = i - pos*96;
        hT[ch*65 + pos] = v;
    }
    __syncthreads();
    {
        int pos = t & 63, part = t >> 6;
        float s1 = 0.f, s2 = 0.f;
        #pragma unroll
        for (int m = 0; m < 6; m++) {
            float v = hT[(part*6 + m)*65 + pos];
            s1 += v; s2 += v*v;
        }
        ps1[part*64 + pos] = s1; ps2[part*64 + pos] = s2;
    }
    __syncthreads();
    if (t < 64) {
        float S1 = 0.f, S2 = 0.f;
        #pragma unroll
        for (int i = 0; i < 16; i++) { S1 += ps1[i*64 + t]; S2 += ps2[i*64 + t]; }
        float mu = S1 * (1.f/96.f);
        float var = S2 * (1.f/96.f) - mu*mu;
        mus[t] = mu; rss[t] = rsqrtf(var + 1e-5f);
    }
    __syncthreads();
    #pragma unroll
    for (int s = 0; s < 6; s++) {
        int i = t + 1024*s;
        int pos = i / 96, ch = i - pos*96;
        hT[ch*65 + pos] = (hT[ch*65 + pos] - mus[pos]) * rss[pos] * lnw[ch] + lnb[ch];
    }
    __syncthreads();

    int w = __builtin_amdgcn_readfirstlane(t >> 6);
    int lane = t & 63;
    int c0 = cgrp*192 + w*12;
    const float* wrows = Win + (size_t)c0*96;   // 12 rows, stride 96, wave-uniform
    float acc[12];
    #pragma unroll
    for (int cc = 0; cc < 12; cc++) acc[cc] = 0.f;
    #pragma unroll 2
    for (int j = 0; j < 96; j++) {
        float u = hT[j*65 + lane];
        #pragma unroll
        for (int cc = 0; cc < 12; cc++) acc[cc] += u * wrows[cc*96 + j];
    }
    size_t p = (size_t)(p0 + lane);
    float* dst = (c0 < 192) ? (xm + p*192 + c0) : (zbuf + p*192 + (c0 - 192));
    #pragma unroll
    for (int q = 0; q < 3; q++)
        *(float4*)&dst[4*q] = make_float4(acc[4*q], acc[4*q+1], acc[4*q+2], acc[4*q+3]);
}

// ---------------- K2: depthwise 3x3 conv + bias + SiLU ----------------
__global__ __launch_bounds__(192) void k2_conv(
    const float* __restrict__ xm, const float* __restrict__ cw,
    const float* __restrict__ cb, float* __restrict__ xconv)
{
    int p = blockIdx.x;
    int d = threadIdx.x;
    int b = p >> 12;
    int l = p & (LL - 1);
    int hh = l >> 6, ww = l & 63;
    float acc = cb[d];
    const float* wd = cw + d*9;
    #pragma unroll
    for (int di = -1; di <= 1; di++) {
        int h2 = hh + di;
        if ((unsigned)h2 < HH) {
            #pragma unroll
            for (int dj = -1; dj <= 1; dj++) {
                int w2 = ww + dj;
                if ((unsigned)w2 < WWD)
                    acc += wd[(di+1)*3 + (dj+1)] * xm[((size_t)b*LL + h2*WWD + w2)*DIN + d];
            }
        }
    }
    xconv[(size_t)p*DIN + d] = silu_f(acc);
}

// ---------------- K3: 4-direction x_proj, swizzled row-major LDS + b128 reads ----------------
__global__ __launch_bounds__(512) void k3_xproj(
    const float* __restrict__ xconv, const float* __restrict__ wT3,
    float* __restrict__ XDK)
{
    __shared__ float uT[64*192];   // [pos][ch], float4-column XOR swizzle
    int t = threadIdx.x;
    int ptile = blockIdx.x >> 1, wgrp = blockIdx.x & 1;
    int p0 = ptile*64;

    #pragma unroll
    for (int s = 0; s < 24; s++) {
        int i = t + 512*s;
        int pos = i / 192, ch = i - pos*192;
        int c4 = (ch >> 2) ^ (pos & 7);            // swizzle 16B quads within 8-quad window
        uT[pos*192 + (c4 << 2) + (ch & 3)] = xconv[(size_t)(p0 + pos)*192 + ch];
    }
    __syncthreads();

    int w = __builtin_amdgcn_readfirstlane(t >> 6);   // 0..7
    int slot = wgrp*8 + w;                             // 0..15
    int k = slot >> 2, cq = slot & 3;
    int lane = t & 63;
    int c0 = cq*12;
    const float* wp = wT3 + (size_t)k*192*CPK + c0;
    const float* urow = uT + lane*192;
    int sw = lane & 7;
    float acc[12];
    #pragma unroll
    for (int cc = 0; cc < 12; cc++) acc[cc] = 0.f;
    #pragma unroll 4
    for (int j4 = 0; j4 < 48; j4++) {
        float4 u4 = *(const float4*)&urow[((j4 ^ sw) << 2)];   // channels 4*j4..4*j4+3
        const float* wrow = wp + (j4*4)*CPK;
        #pragma unroll
        for (int cc = 0; cc < 12; cc++) acc[cc] += u4.x * wrow[cc];
        #pragma unroll
        for (int cc = 0; cc < 12; cc++) acc[cc] += u4.y * wrow[CPK + cc];
        #pragma unroll
        for (int cc = 0; cc < 12; cc++) acc[cc] += u4.z * wrow[2*CPK + cc];
        #pragma unroll
        for (int cc = 0; cc < 12; cc++) acc[cc] += u4.w * wrow[3*CPK + cc];
    }
    int p = p0 + lane;
    int b = p >> 12;
    int s = p & (LL - 1);
    int ts = ((s & 63) << 6) | (s >> 6);
    int l;
    switch (k) {
        case 0: l = s; break;
        case 1: l = ts; break;
        case 2: l = LL - 1 - s; break;
        default: l = LL - 1 - ts; break;
    }
    float* dst = XDK + ((size_t)(b*KD + k)*LL + l)*CPK + c0;
    #pragma unroll
    for (int q = 0; q < 3; q++)
        *(float4*)&dst[4*q] = make_float4(acc[4*q], acc[4*q+1], acc[4*q+2], acc[4*q+3]);
}

// ---------------- K4: scan pass A — h over chunk + S = sum(delta) ----------------
__global__ __launch_bounds__(192) void k4_scanA(
    const float* __restrict__ xconv, const float* __restrict__ XDK,
    const float* __restrict__ dtw, const float* __restrict__ dtb,
    const float* __restrict__ A_log,
    float* __restrict__ Sarr, float* __restrict__ Q)
{
    int blk = blockIdx.x;              // bk*NC + c
    int c  = blk & (NC - 1);
    int bk = blk >> 7;
    int k  = bk & 3;
    int b  = bk >> 2;
    int d  = threadIdx.x;
    float dw[RNK];
    #pragma unroll
    for (int r = 0; r < RNK; r++) dw[r] = dtw[((size_t)k*DIN + d)*RNK + r];
    float bias = dtb[k*DIN + d];
    float A[NST];
    #pragma unroll
    for (int n = 0; n < NST; n++) A[n] = -__expf(A_log[((size_t)k*DIN + d)*NST + n]);
    bool fastA = true;
    #pragma unroll
    for (int n = 1; n < NST; n++)
        fastA = fastA && (fabsf(A[n] - (float)(n+1)*A[0]) <= 1e-4f*(float)(n+1));

    float h[NST];
    #pragma unroll
    for (int n = 0; n < NST; n++) h[n] = 0.f;
    float S = 0.f;

    size_t rb = ((size_t)bk*LL + c*CH)*CPK;
    if (fastA) {
        #pragma unroll 2
        for (int step = 0; step < CH; step++) {
            const float* rec = XDK + rb + step*CPK;
            float dl = bias;
            #pragma unroll
            for (int r = 0; r < RNK; r++) dl += rec[32 + r] * dw[r];
            dl = (dl > 20.f) ? dl : __logf(1.f + __expf(dl));
            int l = c*CH + step;
            float uu = xconv[((size_t)b*LL + pos_of(k, l))*DIN + d];
            float du = dl * uu;
            S += dl;
            float e1 = __expf(dl * A[0]);
            float e2 = e1*e1, e4 = e2*e2;
            float p0 = e1, p1 = e2, p2 = e2*e1, p3 = e4;
            #pragma unroll
            for (int g = 0; g < 4; g++) {
                h[4*g+0] = p0*h[4*g+0] + du*rec[4*g+0];
                h[4*g+1] = p1*h[4*g+1] + du*rec[4*g+1];
                h[4*g+2] = p2*h[4*g+2] + du*rec[4*g+2];
                h[4*g+3] = p3*h[4*g+3] + du*rec[4*g+3];
                if (g < 3) { p0 *= e4; p1 *= e4; p2 *= e4; p3 *= e4; }
            }
        }
    } else {
        #pragma unroll 2
        for (int step = 0; step < CH; step++) {
            const float* rec = XDK + rb + step*CPK;
            float dl = bias;
            #pragma unroll
            for (int r = 0; r < RNK; r++) dl += rec[32 + r] * dw[r];
            dl = (dl > 20.f) ? dl : __logf(1.f + __expf(dl));
            int l = c*CH + step;
            float uu = xconv[((size_t)b*LL + pos_of(k, l))*DIN + d];
            float du = dl * uu;
            S += dl;
            #pragma unroll
            for (int n = 0; n < NST; n++) {
                float a = __expf(dl * A[n]);
                h[n] = a*h[n] + du*rec[n];
            }
        }
    }
    Sarr[(size_t)blk*DIN + d] = S;
    size_t qb = (size_t)blk*NST*DIN + d;
    #pragma unroll
    for (int n = 0; n < NST; n++) Q[qb + n*DIN] = h[n];
}

// ---------------- K5: compose chunk transfers + zero outc ----------------
__global__ __launch_bounds__(256) void k5_scanB(
    const float* __restrict__ A_log, const float* __restrict__ Sarr,
    float* __restrict__ Q, float* __restrict__ outc)
{
    if (blockIdx.x >= SCANB_BLKS) {
        // zero outc: 1,572,864 floats = 393,216 float4; 384 blk x 256 thr x 4 quads
        int zi = (blockIdx.x - SCANB_BLKS)*256 + threadIdx.x;   // 0..98303
        float4* o4 = (float4*)outc;
        float4 z4 = make_float4(0.f, 0.f, 0.f, 0.f);
        #pragma unroll
        for (int j = 0; j < 4; j++) o4[zi + j*98304] = z4;
        return;
    }
    int idx = blockIdx.x*256 + threadIdx.x;
    if (idx >= BB*KD*NST*DIN) return;
    int d = idx % DIN;
    int rest = idx / DIN;
    int n = rest % NST; rest /= NST;
    int k = rest & 3;
    int b = rest >> 2;
    int bk = b*KD + k;
    float A = -__expf(A_log[((size_t)k*DIN + d)*NST + n]);
    size_t qstride = (size_t)NST*DIN;
    size_t qbase = (size_t)bk*NC*qstride + n*DIN + d;
    size_t sbase = (size_t)bk*NC*DIN + d;
    float h = 0.f;
    #pragma unroll 4
    for (int c = 0; c < NC; c++) {
        float s = Sarr[sbase + c*DIN];
        float q = Q[qbase + c*qstride];
        Q[qbase + c*qstride] = h;
        h = __expf(A*s)*h + q;
    }
}

// ---------------- K6: scan pass C — replay, atomic-accumulate y at SPATIAL position ----------------
__global__ __launch_bounds__(192) void k6_scanC(
    const float* __restrict__ xconv, const float* __restrict__ XDK,
    const float* __restrict__ dtw, const float* __restrict__ dtb,
    const float* __restrict__ A_log, const float* __restrict__ Ds,
    const float* __restrict__ Q, float* __restrict__ outc)
{
    int blk = blockIdx.x;
    int c  = blk & (NC - 1);
    int bk = blk >> 7;
    int k  = bk & 3;
    int b  = bk >> 2;
    int d  = threadIdx.x;
    float dw[RNK];
    #pragma unroll
    for (int r = 0; r < RNK; r++) dw[r] = dtw[((size_t)k*DIN + d)*RNK + r];
    float bias = dtb[k*DIN + d];
    float A[NST];
    #pragma unroll
    for (int n = 0; n < NST; n++) A[n] = -__expf(A_log[((size_t)k*DIN + d)*NST + n]);
    bool fastA = true;
    #pragma unroll
    for (int n = 1; n < NST; n++)
        fastA = fastA && (fabsf(A[n] - (float)(n+1)*A[0]) <= 1e-4f*(float)(n+1));
    float h[NST];
    size_t qb = (size_t)blk*NST*DIN + d;
    #pragma unroll
    for (int n = 0; n < NST; n++) h[n] = Q[qb + n*DIN];
    float Dv = Ds[k*DIN + d];

    size_t rb = ((size_t)bk*LL + c*CH)*CPK;
    if (fastA) {
        #pragma unroll 2
        for (int step = 0; step < CH; step++) {
            const float* rec = XDK + rb + step*CPK;
            float dl = bias;
            #pragma unroll
            for (int r = 0; r < RNK; r++) dl += rec[32 + r] * dw[r];
            dl = (dl > 20.f) ? dl : __logf(1.f + __expf(dl));
            int l = c*CH + step;
            int sp = pos_of(k, l);
            float uu = xconv[((size_t)b*LL + sp)*DIN + d];
            float du = dl * uu;
            float e1 = __expf(dl * A[0]);
            float e2 = e1*e1, e4 = e2*e2;
            float p0 = e1, p1 = e2, p2 = e2*e1, p3 = e4;
            float yv = 0.f;
            #pragma unroll
            for (int g = 0; g < 4; g++) {
                h[4*g+0] = p0*h[4*g+0] + du*rec[4*g+0];
                h[4*g+1] = p1*h[4*g+1] + du*rec[4*g+1];
                h[4*g+2] = p2*h[4*g+2] + du*rec[4*g+2];
                h[4*g+3] = p3*h[4*g+3] + du*rec[4*g+3];
                yv += h[4*g+0]*rec[16+4*g+0] + h[4*g+1]*rec[16+4*g+1]
                    + h[4*g+2]*rec[16+4*g+2] + h[4*g+3]*rec[16+4*g+3];
                if (g < 3) { p0 *= e4; p1 *= e4; p2 *= e4; p3 *= e4; }
            }
            atomicAdd(&outc[((size_t)b*LL + sp)*DIN + d], yv + Dv*uu);
        }
    } else {
        #pragma unroll 2
        for (int step = 0; step < CH; step++) {
            const float* rec = XDK + rb + step*CPK;
            float dl = bias;
            #pragma unroll
            for (int r = 0; r < RNK; r++) dl += rec[32 + r] * dw[r];
            dl = (dl > 20.f) ? dl : __logf(1.f + __expf(dl));
            int l = c*CH + step;
            int sp = pos_of(k, l);
            float uu = xconv[((size_t)b*LL + sp)*DIN + d];
            float du = dl * uu;
            float yv = 0.f;
            #pragma unroll
            for (int n = 0; n < NST; n++) {
                float a = __expf(dl * A[n]);
                h[n] = a*h[n] + du*rec[n];
                yv += h[n] * rec[16 + n];
            }
            atomicAdd(&outc[((size_t)b*LL + sp)*DIN + d], yv + Dv*uu);
        }
    }
}

// ---------------- K7: LN(192), gate, out_proj, residual (compact outc input) ----------------
__global__ __launch_bounds__(512) void k7_out(
    const float* __restrict__ outc, const float* __restrict__ zbuf,
    const float* __restrict__ diff, const float* __restrict__ onw,
    const float* __restrict__ onb, const float* __restrict__ WoutT,
    float* __restrict__ out)
{
    __shared__ float gT[192*65];
    __shared__ float ps1[8*64], ps2[8*64];
    __shared__ float mus[64], rss[64];
    int t = threadIdx.x;
    int ptile = blockIdx.x >> 1, chalf = blockIdx.x & 1;
    int p0 = ptile*64;

    #pragma unroll
    for (int s = 0; s < 24; s++) {
        int i = t + 512*s;
        float yc = outc[(size_t)p0*DIN + i];
        int pos = i / 192, ch = i - pos*192;
        gT[ch*65 + pos] = yc;
    }
    __syncthreads();
    {
        int pos = t & 63, part = t >> 6;   // 8 parts x 24 channels
        float s1 = 0.f, s2 = 0.f;
        #pragma unroll
        for (int m = 0; m < 24; m++) {
            float v = gT[(part*24 + m)*65 + pos];
            s1 += v; s2 += v*v;
        }
        ps1[part*64 + pos] = s1; ps2[part*64 + pos] = s2;
    }
    __syncthreads();
    if (t < 64) {
        float S1 = 0.f, S2 = 0.f;
        #pragma unroll
        for (int i = 0; i < 8; i++) { S1 += ps1[i*64 + t]; S2 += ps2[i*64 + t]; }
        float mu = S1 * (1.f/192.f);
        float var = S2 * (1.f/192.f) - mu*mu;
        mus[t] = mu; rss[t] = rsqrtf(var + 1e-5f);
    }
    __syncthreads();
    #pragma unroll
    for (int s = 0; s < 24; s++) {
        int i = t + 512*s;
        int pos = i / 192, ch = i - pos*192;
        float v = gT[ch*65 + pos];
        float yn = (v - mus[pos]) * rss[pos] * onw[ch] + onb[ch];
        float z = zbuf[(size_t)p0*DIN + i];
        gT[ch*65 + pos] = yn * silu_f(z);
    }
    __syncthreads();

    int w = __builtin_amdgcn_readfirstlane(t >> 6);   // 0..7
    int lane = t & 63;
    int c0 = chalf*48 + w*6;                          // 8 waves x 6 output cols
    const float* wp = WoutT + c0;
    float acc[6];
    #pragma unroll
    for (int cc = 0; cc < 6; cc++) acc[cc] = 0.f;
    #pragma unroll 4
    for (int j = 0; j < 192; j++) {
        float u = gT[j*65 + lane];
        const float* wrow = wp + j*96;
        #pragma unroll
        for (int cc = 0; cc < 6; cc++) acc[cc] += u * wrow[cc];
    }
    size_t p = (size_t)(p0 + lane);
    #pragma unroll
    for (int q = 0; q < 3; q++) {
        float2 dv = *(const float2*)&diff[p*96 + c0 + 2*q];
        *(float2*)&out[p*96 + c0 + 2*q] =
            make_float2(acc[2*q] + dv.x, acc[2*q+1] + dv.y);
    }
}

extern "C" void kernel_launch(void* const* d_in, const int* in_sizes, int n_in,
                              void* d_out, int out_size, void* d_ws, size_t ws_size,
                              hipStream_t stream)
{
    const float* x       = (const float*)d_in[0];
    const float* y       = (const float*)d_in[1];
    const float* ln_w    = (const float*)d_in[2];
    const float* ln_b    = (const float*)d_in[3];
    const float* in_proj = (const float*)d_in[4];
    const float* conv_w  = (const float*)d_in[5];
    const float* conv_b  = (const float*)d_in[6];
    const float* x_proj  = (const float*)d_in[7];
    const float* dt_w    = (const float*)d_in[8];
    const float* dt_b    = (const float*)d_in[9];
    const float* A_log   = (const float*)d_in[10];
    const float* Ds      = (const float*)d_in[11];
    const float* onw     = (const float*)d_in[12];
    const float* onb     = (const float*)d_in[13];
    const float* out_w   = (const float*)d_in[14];
    float* out = (float*)d_out;

    float* ws    = (float*)d_ws;
    float* diff  = ws;                       // 786432
    float* zbuf  = diff  + 786432;           // 1572864
    float* xm    = zbuf  + 1572864;          // 1572864
    float* xconv = xm    + 1572864;          // 1572864
    float* XDK   = xconv + 1572864;          // 1572864
    float* outc  = XDK   + 1572864;          // 1572864 (compact [B,L,192])
    float* Qbuf  = outc  + 1572864;          // 3145728 (1024 blk x 16 x 192)
    float* Sarr  = Qbuf  + 3145728;          // 196608
    float* WoutT = Sarr  + 196608;           // 18432
    float* wT3   = WoutT + 18432;            // 36864

    const int BL = BB * LL;                  // 8192

    hipLaunchKernelGGL(k1_ln_inproj, dim3(BL/64*2), dim3(1024), 0, stream,
                       x, y, ln_w, ln_b, in_proj, out_w, x_proj,
                       diff, xm, zbuf, wT3, WoutT);
    hipLaunchKernelGGL(k2_conv, dim3(BL), dim3(DIN), 0, stream,
                       xm, conv_w, conv_b, xconv);
    hipLaunchKernelGGL(k3_xproj, dim3(BL/64*2), dim3(512), 0, stream,
                       xconv, wT3, XDK);
    hipLaunchKernelGGL(k4_scanA, dim3(BB*KD*NC), dim3(DIN), 0, stream,
                       xconv, XDK, dt_w, dt_b, A_log, Sarr, Qbuf);
    hipLaunchKernelGGL(k5_scanB, dim3(SCANB_BLKS + ZERO_BLKS), dim3(256), 0, stream,
                       A_log, Sarr, Qbuf, outc);
    hipLaunchKernelGGL(k6_scanC, dim3(BB*KD*NC), dim3(DIN), 0, stream,
                       xconv, XDK, dt_w, dt_b, A_log, Ds, Qbuf, outc);
    hipLaunchKernelGGL(k7_out, dim3(BL/64*2), dim3(512), 0, stream,
                       outc, zbuf, diff, onw, onb, WoutT, out);
}